// Round 1
// baseline (1067.267 us; speedup 1.0000x reference)
//
#include <hip/hip_runtime.h>
#include <math.h>

// TAGConv 2-layer GNN on MI355X.
// Strategy: build CSR (by target) once per call -> atomic-free propagation,
// fused per-hop matmul accumulation, fused epilogues (bias+relu, bias+log_softmax).

#define N_NODES 50000
#define N_EDGES 800000
#define FEAT    128      // F_IN == HID == 128 (all propagated tensors are 128-wide)

// ---------------- small utility kernels ----------------

__global__ void zero_f_kernel(float* __restrict__ p, int n) {
    int i = blockIdx.x * 256 + threadIdx.x;
    if (i < n) p[i] = 0.f;
}

__global__ void count_deg_kernel(const int* __restrict__ col, float* __restrict__ deg, int e) {
    int i = blockIdx.x * 256 + threadIdx.x;
    if (i < e) atomicAdd(&deg[col[i]], 1.f);
}

__global__ void dinv_kernel(const float* __restrict__ deg, float* __restrict__ dinv, int n) {
    int i = blockIdx.x * 256 + threadIdx.x;
    if (i < n) {
        float d = deg[i];
        dinv[i] = (d > 0.f) ? (1.0f / sqrtf(d)) : 0.f;
    }
}

// Exclusive scan of (int)deg -> off[0..n], cursor[i]=off[i]. Single block, 1024 threads.
__global__ void scan_kernel(const float* __restrict__ deg, int* __restrict__ off,
                            int* __restrict__ cursor, int n) {
    __shared__ int sd[1024];
    __shared__ int carry;
    int tid = threadIdx.x;
    if (tid == 0) carry = 0;
    __syncthreads();
    for (int base = 0; base < n; base += 1024) {
        int i = base + tid;
        int v = (i < n) ? (int)deg[i] : 0;
        sd[tid] = v;
        __syncthreads();
        for (int o = 1; o < 1024; o <<= 1) {
            int t = (tid >= o) ? sd[tid - o] : 0;
            __syncthreads();
            sd[tid] += t;
            __syncthreads();
        }
        int excl = sd[tid] - v;
        if (i < n) { off[i] = carry + excl; cursor[i] = carry + excl; }
        int tot = sd[1023];
        __syncthreads();
        if (tid == 0) carry += tot;
        __syncthreads();
    }
    if (tid == 0) off[n] = carry;
}

__global__ void scatter_csr_kernel(const int* __restrict__ row, const int* __restrict__ col,
                                   const float* __restrict__ dinv, int* __restrict__ cursor,
                                   int* __restrict__ src, float* __restrict__ w, int e) {
    int i = blockIdx.x * 256 + threadIdx.x;
    if (i < e) {
        int r = row[i], c = col[i];
        int p = atomicAdd(&cursor[c], 1);
        src[p] = r;
        w[p] = dinv[r] * dinv[c];
    }
}

// ---------------- propagation: out[i] = sum_{e: col==i} w[e] * h[src[e]] ----------------
// One 64-lane wave per target node; lane handles 2 floats (float2) of the 128-wide row.
__global__ void prop_kernel(const float* __restrict__ h, const int* __restrict__ off,
                            const int* __restrict__ src, const float* __restrict__ w,
                            float* __restrict__ out) {
    int node = blockIdx.x * 4 + (threadIdx.x >> 6);
    int lane = threadIdx.x & 63;
    int s = off[node], e = off[node + 1];
    const float2* h2 = (const float2*)h;
    float2 acc = make_float2(0.f, 0.f);
    for (int j = s; j < e; ++j) {
        int sr = src[j];
        float wt = w[j];
        float2 v = h2[sr * 64 + lane];
        acc.x += wt * v.x;
        acc.y += wt * v.y;
    }
    ((float2*)out)[node * 64 + lane] = acc;
}

// ---------------- fused matmul: out[16 x OUTC tile] (+)= h_tile(16x128) @ W(128xOUTC) ----
// EPI: 0 = none, 1 = +bias, relu, 2 = +bias, log_softmax (OUTC==64, one wave)
template <int OUTC, bool ACCUM, int EPI>
__global__ void mm_kernel(const float* __restrict__ h, const float* __restrict__ W,
                          const float* __restrict__ bias, float* __restrict__ out) {
    __shared__ float lds[16 * 128];
    const int tid = threadIdx.x;          // tid == output column
    const int row0 = blockIdx.x * 16;

    // stage 16 rows of h (coalesced float4)
    const float4* h4 = (const float4*)(h + row0 * 128);
    float4* lds4 = (float4*)lds;
    for (int idx = tid; idx < 16 * 128 / 4; idx += OUTC) lds4[idx] = h4[idx];
    __syncthreads();

    float acc[16];
#pragma unroll
    for (int r = 0; r < 16; ++r) acc[r] = 0.f;

    for (int c4 = 0; c4 < 128; c4 += 4) {
        float w0 = W[(c4 + 0) * OUTC + tid];
        float w1 = W[(c4 + 1) * OUTC + tid];
        float w2 = W[(c4 + 2) * OUTC + tid];
        float w3 = W[(c4 + 3) * OUTC + tid];
#pragma unroll
        for (int r = 0; r < 16; ++r) {
            float4 hv = *(const float4*)&lds[r * 128 + c4];
            acc[r] += hv.x * w0 + hv.y * w1 + hv.z * w2 + hv.w * w3;
        }
    }

    if (EPI == 0) {
#pragma unroll
        for (int r = 0; r < 16; ++r) {
            int o = (row0 + r) * OUTC + tid;
            float v = acc[r];
            if (ACCUM) v += out[o];
            out[o] = v;
        }
    } else if (EPI == 1) {
        float b = bias[tid];
#pragma unroll
        for (int r = 0; r < 16; ++r) {
            int o = (row0 + r) * OUTC + tid;
            float v = acc[r] + out[o] + b;
            out[o] = fmaxf(v, 0.f);
        }
    } else {  // EPI == 2: bias + log_softmax over the 64 columns (one wave)
        float b = bias[tid];
#pragma unroll
        for (int r = 0; r < 16; ++r) {
            int o = (row0 + r) * OUTC + tid;
            float v = acc[r] + out[o] + b;
            float m = v;
            for (int s = 32; s > 0; s >>= 1) m = fmaxf(m, __shfl_xor(m, s));
            float ex = expf(v - m);
            float su = ex;
            for (int s = 32; s > 0; s >>= 1) su += __shfl_xor(su, s);
            out[o] = (v - m) - logf(su);
        }
    }
}

// ---------------- launch ----------------

extern "C" void kernel_launch(void* const* d_in, const int* in_sizes, int n_in,
                              void* d_out, int out_size, void* d_ws, size_t ws_size,
                              hipStream_t stream) {
    const float* x  = (const float*)d_in[0];
    const int*   ei = (const int*)d_in[1];
    const float* W1 = (const float*)d_in[2];
    const float* b1 = (const float*)d_in[3];
    const float* W2 = (const float*)d_in[4];
    const float* b2 = (const float*)d_in[5];
    float* out = (float*)d_out;

    const int* row = ei;             // edge_index[0]
    const int* col = ei + N_EDGES;   // edge_index[1]

    // workspace layout (512B aligned)
    char* ws = (char*)d_ws;
    size_t o = 0;
    auto carve = [&](size_t bytes) {
        void* p = ws + o;
        o = (o + bytes + 511) & ~(size_t)511;
        return p;
    };
    float* deg    = (float*)carve(N_NODES * 4);
    float* dinv   = (float*)carve(N_NODES * 4);
    int*   off    = (int*)carve((N_NODES + 1) * 4);
    int*   cursor = (int*)carve(N_NODES * 4);
    int*   csrs   = (int*)carve(N_EDGES * 4);
    float* csrw   = (float*)carve(N_EDGES * 4);
    float* A      = (float*)carve((size_t)N_NODES * FEAT * 4);
    float* B      = (float*)carve((size_t)N_NODES * FEAT * 4);
    float* hid    = (float*)carve((size_t)N_NODES * FEAT * 4);

    const int nb_n = (N_NODES + 255) / 256;   // 196
    const int nb_e = (N_EDGES + 255) / 256;   // 3125
    const int nb_mm = N_NODES / 16;           // 3125
    const int nb_prop = N_NODES / 4;          // 12500

    // graph preprocessing
    zero_f_kernel<<<nb_n, 256, 0, stream>>>(deg, N_NODES);
    count_deg_kernel<<<nb_e, 256, 0, stream>>>(col, deg, N_EDGES);
    dinv_kernel<<<nb_n, 256, 0, stream>>>(deg, dinv, N_NODES);
    scan_kernel<<<1, 1024, 0, stream>>>(deg, off, cursor, N_NODES);
    scatter_csr_kernel<<<nb_e, 256, 0, stream>>>(row, col, dinv, cursor, csrs, csrw, N_EDGES);

    // ----- layer 1: hid = relu(sum_k (A^k x) @ W1[k] + b1) -----
    mm_kernel<128, false, 0><<<nb_mm, 128, 0, stream>>>(x, W1 + 0 * 128 * 128, nullptr, hid);
    prop_kernel<<<nb_prop, 256, 0, stream>>>(x, off, csrs, csrw, A);
    mm_kernel<128, true, 0><<<nb_mm, 128, 0, stream>>>(A, W1 + 1 * 128 * 128, nullptr, hid);
    prop_kernel<<<nb_prop, 256, 0, stream>>>(A, off, csrs, csrw, B);
    mm_kernel<128, true, 0><<<nb_mm, 128, 0, stream>>>(B, W1 + 2 * 128 * 128, nullptr, hid);
    prop_kernel<<<nb_prop, 256, 0, stream>>>(B, off, csrs, csrw, A);
    mm_kernel<128, true, 1><<<nb_mm, 128, 0, stream>>>(A, W1 + 3 * 128 * 128, b1, hid);

    // ----- layer 2: out = log_softmax(sum_k (A^k hid) @ W2[k] + b2) -----
    mm_kernel<64, false, 0><<<nb_mm, 64, 0, stream>>>(hid, W2 + 0 * 128 * 64, nullptr, out);
    prop_kernel<<<nb_prop, 256, 0, stream>>>(hid, off, csrs, csrw, A);
    mm_kernel<64, true, 0><<<nb_mm, 64, 0, stream>>>(A, W2 + 1 * 128 * 64, nullptr, out);
    prop_kernel<<<nb_prop, 256, 0, stream>>>(A, off, csrs, csrw, B);
    mm_kernel<64, true, 0><<<nb_mm, 64, 0, stream>>>(B, W2 + 2 * 128 * 64, nullptr, out);
    prop_kernel<<<nb_prop, 256, 0, stream>>>(B, off, csrs, csrw, A);
    mm_kernel<64, true, 2><<<nb_mm, 64, 0, stream>>>(A, W2 + 3 * 128 * 64, b2, out);
}

// Round 2
// 790.623 us; speedup vs baseline: 1.3499x; 1.3499x over previous
//
#include <hip/hip_runtime.h>
#include <math.h>

// TAGConv 2-layer GNN on MI355X.
// R2: tiled LDS matmul (80x64 tile, W+h staged in LDS, 5x4 reg-block) replacing
// the latency-bound mm (VALUBusy was 7.8%); two-level scan replacing the 96us
// single-block scan; prop unrolled x2.

#define N_NODES 50000
#define N_EDGES 800000
#define FEAT    128
#define NB_SCAN 196          // ceil(50000/256)

// ---------------- graph preprocessing ----------------

__global__ void count_deg_kernel(const int* __restrict__ col, int* __restrict__ deg, int e) {
    int i = blockIdx.x * 256 + threadIdx.x;
    if (i < e) atomicAdd(&deg[col[i]], 1);
}

// per-block sum of deg -> bsum[b]; also dinv = 1/sqrt(deg)
__global__ void scan1_kernel(const int* __restrict__ deg, int* __restrict__ bsum,
                             float* __restrict__ dinv) {
    __shared__ int sd[256];
    int tid = threadIdx.x;
    int i = blockIdx.x * 256 + tid;
    int v = (i < N_NODES) ? deg[i] : 0;
    if (i < N_NODES) dinv[i] = (v > 0) ? (1.0f / sqrtf((float)v)) : 0.f;
    sd[tid] = v;
    __syncthreads();
    for (int o = 128; o > 0; o >>= 1) {
        if (tid < o) sd[tid] += sd[tid + o];
        __syncthreads();
    }
    if (tid == 0) bsum[blockIdx.x] = sd[0];
}

// exclusive scan of bsum[0..NB_SCAN) in place (single block, 256 threads)
__global__ void scan2_kernel(int* __restrict__ bsum) {
    __shared__ int sd[256];
    int tid = threadIdx.x;
    int v = (tid < NB_SCAN) ? bsum[tid] : 0;
    sd[tid] = v;
    __syncthreads();
    for (int o = 1; o < 256; o <<= 1) {
        int t = (tid >= o) ? sd[tid - o] : 0;
        __syncthreads();
        sd[tid] += t;
        __syncthreads();
    }
    if (tid < NB_SCAN) bsum[tid] = sd[tid] - v;   // exclusive
}

// off[i] = bsum[b] + exclusive_scan_within_block(deg); cursor=off; off[N]=E
__global__ void scan3_kernel(const int* __restrict__ deg, const int* __restrict__ bsum,
                             int* __restrict__ off, int* __restrict__ cursor) {
    __shared__ int sd[256];
    int tid = threadIdx.x;
    int i = blockIdx.x * 256 + tid;
    int v = (i < N_NODES) ? deg[i] : 0;
    sd[tid] = v;
    __syncthreads();
    for (int o = 1; o < 256; o <<= 1) {
        int t = (tid >= o) ? sd[tid - o] : 0;
        __syncthreads();
        sd[tid] += t;
        __syncthreads();
    }
    if (i < N_NODES) {
        int val = bsum[blockIdx.x] + sd[tid] - v;
        off[i] = val;
        cursor[i] = val;
    }
    if (i == N_NODES - 1) off[N_NODES] = N_EDGES;
}

__global__ void scatter_csr_kernel(const int* __restrict__ row, const int* __restrict__ col,
                                   const float* __restrict__ dinv, int* __restrict__ cursor,
                                   int* __restrict__ src, float* __restrict__ w, int e) {
    int i = blockIdx.x * 256 + threadIdx.x;
    if (i < e) {
        int r = row[i], c = col[i];
        int p = atomicAdd(&cursor[c], 1);
        src[p] = r;
        w[p] = dinv[r] * dinv[c];
    }
}

// ---------------- propagation: out[i] = sum_{e: col==i} w[e] * h[src[e]] ----------------
// One 64-lane wave per target node; lane handles a float2 of the 128-wide row.
__global__ void prop_kernel(const float* __restrict__ h, const int* __restrict__ off,
                            const int* __restrict__ src, const float* __restrict__ w,
                            float* __restrict__ out) {
    int node = blockIdx.x * 4 + (threadIdx.x >> 6);
    int lane = threadIdx.x & 63;
    int s = off[node], e = off[node + 1];
    const float2* h2 = (const float2*)h;
    float2 acc = make_float2(0.f, 0.f);
    int j = s;
    for (; j + 1 < e; j += 2) {
        int s0 = src[j], s1 = src[j + 1];
        float w0 = w[j], w1 = w[j + 1];
        float2 v0 = h2[s0 * 64 + lane];
        float2 v1 = h2[s1 * 64 + lane];
        acc.x += w0 * v0.x + w1 * v1.x;
        acc.y += w0 * v0.y + w1 * v1.y;
    }
    if (j < e) {
        int s0 = src[j];
        float w0 = w[j];
        float2 v0 = h2[s0 * 64 + lane];
        acc.x += w0 * v0.x;
        acc.y += w0 * v0.y;
    }
    ((float2*)out)[node * 64 + lane] = acc;
}

// ---------------- tiled matmul: out[80 x 64 tile] (+)= h(80x128) @ W[:, cb*64:+64] ------
// WSTRIDE = total output cols (= W row stride = out row stride).
// EPI: 0 = none, 1 = +bias,relu, 2 = +bias,log_softmax (WSTRIDE==64 only)
// 256 threads: tx = tid&15 (col4), ty = tid>>4 (5-row group). grid (625, WSTRIDE/64).
template <int WSTRIDE, bool ACCUM, int EPI>
__global__ __launch_bounds__(256) void mm_tiled(const float* __restrict__ h,
                                                const float* __restrict__ W,
                                                const float* __restrict__ bias,
                                                float* __restrict__ out) {
    __shared__ float hs[80 * 132];   // padded stride 132 -> conflict-free b128 reads
    __shared__ float wsh[128 * 64];
    const int tid = threadIdx.x;
    const int tx = tid & 15;
    const int ty = tid >> 4;
    const int row0 = blockIdx.x * 80;
    const int cb = blockIdx.y;

    // stage h tile (2560 float4, coalesced)
    const float4* srcv = (const float4*)(h + (size_t)row0 * 128);
    for (int i = tid; i < 2560; i += 256) {
        int r = i >> 5, c = i & 31;
        *(float4*)&hs[r * 132 + c * 4] = srcv[i];
    }
    // stage W panel: rows 0..127, cols cb*64..cb*64+63
    for (int i = tid; i < 2048; i += 256) {
        int k = i >> 4, c = i & 15;
        *(float4*)&wsh[k * 64 + c * 4] =
            ((const float4*)(W + (size_t)k * WSTRIDE + cb * 64))[c];
    }
    __syncthreads();

    float acc[5][4];
#pragma unroll
    for (int r = 0; r < 5; ++r)
#pragma unroll
        for (int j = 0; j < 4; ++j) acc[r][j] = 0.f;

    const int rbase = ty * 5;
#pragma unroll 8
    for (int k4 = 0; k4 < 32; ++k4) {
        float4 wv0 = *(const float4*)&wsh[(k4 * 4 + 0) * 64 + tx * 4];
        float4 wv1 = *(const float4*)&wsh[(k4 * 4 + 1) * 64 + tx * 4];
        float4 wv2 = *(const float4*)&wsh[(k4 * 4 + 2) * 64 + tx * 4];
        float4 wv3 = *(const float4*)&wsh[(k4 * 4 + 3) * 64 + tx * 4];
#pragma unroll
        for (int r = 0; r < 5; ++r) {
            float4 hv = *(const float4*)&hs[(rbase + r) * 132 + k4 * 4];
            acc[r][0] += hv.x * wv0.x + hv.y * wv1.x + hv.z * wv2.x + hv.w * wv3.x;
            acc[r][1] += hv.x * wv0.y + hv.y * wv1.y + hv.z * wv2.y + hv.w * wv3.y;
            acc[r][2] += hv.x * wv0.z + hv.y * wv1.z + hv.z * wv2.z + hv.w * wv3.z;
            acc[r][3] += hv.x * wv0.w + hv.y * wv1.w + hv.z * wv2.w + hv.w * wv3.w;
        }
    }

    const int colg = cb * 64 + tx * 4;
    float4 bv = make_float4(0.f, 0.f, 0.f, 0.f);
    if (EPI != 0) bv = *(const float4*)&bias[colg];

#pragma unroll
    for (int r = 0; r < 5; ++r) {
        int rowg = row0 + rbase + r;
        float* op = out + (size_t)rowg * WSTRIDE + colg;
        float4 v = make_float4(acc[r][0], acc[r][1], acc[r][2], acc[r][3]);
        if (ACCUM) {
            float4 ov = *(const float4*)op;
            v.x += ov.x; v.y += ov.y; v.z += ov.z; v.w += ov.w;
        }
        if (EPI == 0) {
            *(float4*)op = v;
        } else if (EPI == 1) {
            v.x = fmaxf(v.x + bv.x, 0.f);
            v.y = fmaxf(v.y + bv.y, 0.f);
            v.z = fmaxf(v.z + bv.z, 0.f);
            v.w = fmaxf(v.w + bv.w, 0.f);
            *(float4*)op = v;
        } else {  // EPI == 2: bias + log_softmax over 64 cols (16 lanes x 4 each)
            v.x += bv.x; v.y += bv.y; v.z += bv.z; v.w += bv.w;
            float m = fmaxf(fmaxf(v.x, v.y), fmaxf(v.z, v.w));
            m = fmaxf(m, __shfl_xor(m, 1));
            m = fmaxf(m, __shfl_xor(m, 2));
            m = fmaxf(m, __shfl_xor(m, 4));
            m = fmaxf(m, __shfl_xor(m, 8));
            float su = expf(v.x - m) + expf(v.y - m) + expf(v.z - m) + expf(v.w - m);
            su += __shfl_xor(su, 1);
            su += __shfl_xor(su, 2);
            su += __shfl_xor(su, 4);
            su += __shfl_xor(su, 8);
            float l = m + logf(su);
            v.x -= l; v.y -= l; v.z -= l; v.w -= l;
            *(float4*)op = v;
        }
    }
}

// ---------------- launch ----------------

extern "C" void kernel_launch(void* const* d_in, const int* in_sizes, int n_in,
                              void* d_out, int out_size, void* d_ws, size_t ws_size,
                              hipStream_t stream) {
    const float* x  = (const float*)d_in[0];
    const int*   ei = (const int*)d_in[1];
    const float* W1 = (const float*)d_in[2];
    const float* b1 = (const float*)d_in[3];
    const float* W2 = (const float*)d_in[4];
    const float* b2 = (const float*)d_in[5];
    float* out = (float*)d_out;

    const int* row = ei;             // edge_index[0]
    const int* col = ei + N_EDGES;   // edge_index[1]

    char* ws_base = (char*)d_ws;
    size_t o = 0;
    auto carve = [&](size_t bytes) {
        void* p = ws_base + o;
        o = (o + bytes + 511) & ~(size_t)511;
        return p;
    };
    int*   deg    = (int*)carve(N_NODES * 4);
    float* dinv   = (float*)carve(N_NODES * 4);
    int*   off    = (int*)carve((N_NODES + 1) * 4);
    int*   cursor = (int*)carve(N_NODES * 4);
    int*   bsum   = (int*)carve(NB_SCAN * 4);
    int*   csrs   = (int*)carve(N_EDGES * 4);
    float* csrw   = (float*)carve(N_EDGES * 4);
    float* A      = (float*)carve((size_t)N_NODES * FEAT * 4);
    float* B      = (float*)carve((size_t)N_NODES * FEAT * 4);
    float* hid    = (float*)carve((size_t)N_NODES * FEAT * 4);

    const int nb_e = (N_EDGES + 255) / 256;   // 3125
    const int nb_prop = N_NODES / 4;          // 12500

    // graph preprocessing
    hipMemsetAsync(deg, 0, N_NODES * 4, stream);
    count_deg_kernel<<<nb_e, 256, 0, stream>>>(col, deg, N_EDGES);
    scan1_kernel<<<NB_SCAN, 256, 0, stream>>>(deg, bsum, dinv);
    scan2_kernel<<<1, 256, 0, stream>>>(bsum);
    scan3_kernel<<<NB_SCAN, 256, 0, stream>>>(deg, bsum, off, cursor);
    scatter_csr_kernel<<<nb_e, 256, 0, stream>>>(row, col, dinv, cursor, csrs, csrw, N_EDGES);

    dim3 g1(625, 2), g2(625, 1);

    // ----- layer 1: hid = relu(sum_k (A^k x) @ W1[k] + b1) -----
    mm_tiled<128, false, 0><<<g1, 256, 0, stream>>>(x, W1 + 0 * 128 * 128, nullptr, hid);
    prop_kernel<<<nb_prop, 256, 0, stream>>>(x, off, csrs, csrw, A);
    mm_tiled<128, true, 0><<<g1, 256, 0, stream>>>(A, W1 + 1 * 128 * 128, nullptr, hid);
    prop_kernel<<<nb_prop, 256, 0, stream>>>(A, off, csrs, csrw, B);
    mm_tiled<128, true, 0><<<g1, 256, 0, stream>>>(B, W1 + 2 * 128 * 128, nullptr, hid);
    prop_kernel<<<nb_prop, 256, 0, stream>>>(B, off, csrs, csrw, A);
    mm_tiled<128, true, 1><<<g1, 256, 0, stream>>>(A, W1 + 3 * 128 * 128, b1, hid);

    // ----- layer 2: out = log_softmax(sum_k (A^k hid) @ W2[k] + b2) -----
    mm_tiled<64, false, 0><<<g2, 256, 0, stream>>>(hid, W2 + 0 * 128 * 64, nullptr, out);
    prop_kernel<<<nb_prop, 256, 0, stream>>>(hid, off, csrs, csrw, A);
    mm_tiled<64, true, 0><<<g2, 256, 0, stream>>>(A, W2 + 1 * 128 * 64, nullptr, out);
    prop_kernel<<<nb_prop, 256, 0, stream>>>(A, off, csrs, csrw, B);
    mm_tiled<64, true, 0><<<g2, 256, 0, stream>>>(B, W2 + 2 * 128 * 64, nullptr, out);
    prop_kernel<<<nb_prop, 256, 0, stream>>>(B, off, csrs, csrw, A);
    mm_tiled<64, true, 2><<<g2, 256, 0, stream>>>(A, W2 + 3 * 128 * 64, b2, out);
}

// Round 3
// 715.074 us; speedup vs baseline: 1.4925x; 1.1057x over previous
//
#include <hip/hip_runtime.h>
#include <math.h>

// TAGConv 2-layer GNN on MI355X.
// R3: (a) one fused K=512 matmul per layer (x,Ax,A2x,A3x staged hop-by-hop in
// LDS, single register accumulator) -> kills 6 RMW accumulate passes;
// (b) prop unrolled x4 with packed (src,w) int2 edge meta for gather ILP.

#define N_NODES 50000
#define N_EDGES 800000
#define FEAT    128
#define NB_SCAN 196          // ceil(50000/256)

// ---------------- graph preprocessing ----------------

__global__ void count_deg_kernel(const int* __restrict__ col, int* __restrict__ deg, int e) {
    int i = blockIdx.x * 256 + threadIdx.x;
    if (i < e) atomicAdd(&deg[col[i]], 1);
}

// per-block sum of deg -> bsum[b]; also dinv = 1/sqrt(deg)
__global__ void scan1_kernel(const int* __restrict__ deg, int* __restrict__ bsum,
                             float* __restrict__ dinv) {
    __shared__ int sd[256];
    int tid = threadIdx.x;
    int i = blockIdx.x * 256 + tid;
    int v = (i < N_NODES) ? deg[i] : 0;
    if (i < N_NODES) dinv[i] = (v > 0) ? (1.0f / sqrtf((float)v)) : 0.f;
    sd[tid] = v;
    __syncthreads();
    for (int o = 128; o > 0; o >>= 1) {
        if (tid < o) sd[tid] += sd[tid + o];
        __syncthreads();
    }
    if (tid == 0) bsum[blockIdx.x] = sd[0];
}

// exclusive scan of bsum[0..NB_SCAN) in place (single block, 256 threads)
__global__ void scan2_kernel(int* __restrict__ bsum) {
    __shared__ int sd[256];
    int tid = threadIdx.x;
    int v = (tid < NB_SCAN) ? bsum[tid] : 0;
    sd[tid] = v;
    __syncthreads();
    for (int o = 1; o < 256; o <<= 1) {
        int t = (tid >= o) ? sd[tid - o] : 0;
        __syncthreads();
        sd[tid] += t;
        __syncthreads();
    }
    if (tid < NB_SCAN) bsum[tid] = sd[tid] - v;   // exclusive
}

// off[i] = bsum[b] + exclusive_scan_within_block(deg); cursor=off; off[N]=E
__global__ void scan3_kernel(const int* __restrict__ deg, const int* __restrict__ bsum,
                             int* __restrict__ off, int* __restrict__ cursor) {
    __shared__ int sd[256];
    int tid = threadIdx.x;
    int i = blockIdx.x * 256 + tid;
    int v = (i < N_NODES) ? deg[i] : 0;
    sd[tid] = v;
    __syncthreads();
    for (int o = 1; o < 256; o <<= 1) {
        int t = (tid >= o) ? sd[tid - o] : 0;
        __syncthreads();
        sd[tid] += t;
        __syncthreads();
    }
    if (i < N_NODES) {
        int val = bsum[blockIdx.x] + sd[tid] - v;
        off[i] = val;
        cursor[i] = val;
    }
    if (i == N_NODES - 1) off[N_NODES] = N_EDGES;
}

// meta[p] = (src, bits(dinv[src]*dinv[dst])) -- single 8B load per edge in prop
__global__ void scatter_csr_kernel(const int* __restrict__ row, const int* __restrict__ col,
                                   const float* __restrict__ dinv, int* __restrict__ cursor,
                                   int2* __restrict__ meta, int e) {
    int i = blockIdx.x * 256 + threadIdx.x;
    if (i < e) {
        int r = row[i], c = col[i];
        int p = atomicAdd(&cursor[c], 1);
        float w = dinv[r] * dinv[c];
        meta[p] = make_int2(r, __float_as_int(w));
    }
}

// ---------------- propagation: out[i] = sum_{e: col==i} w[e] * h[src[e]] ----------------
// One 64-lane wave per target node; lane covers a float2 of the 128-wide row.
// 4 independent gathers in flight per wave.
__global__ void prop_kernel(const float* __restrict__ h, const int* __restrict__ off,
                            const int2* __restrict__ meta, float* __restrict__ out) {
    int node = blockIdx.x * 4 + (threadIdx.x >> 6);
    int lane = threadIdx.x & 63;
    int s = off[node], e = off[node + 1];
    const float2* h2 = (const float2*)h;
    float2 a0 = make_float2(0.f, 0.f), a1 = make_float2(0.f, 0.f);
    int j = s;
    for (; j + 3 < e; j += 4) {
        int2 m0 = meta[j], m1 = meta[j + 1], m2 = meta[j + 2], m3 = meta[j + 3];
        float2 v0 = h2[m0.x * 64 + lane];
        float2 v1 = h2[m1.x * 64 + lane];
        float2 v2 = h2[m2.x * 64 + lane];
        float2 v3 = h2[m3.x * 64 + lane];
        float w0 = __int_as_float(m0.y), w1 = __int_as_float(m1.y);
        float w2 = __int_as_float(m2.y), w3 = __int_as_float(m3.y);
        a0.x += w0 * v0.x + w1 * v1.x;
        a0.y += w0 * v0.y + w1 * v1.y;
        a1.x += w2 * v2.x + w3 * v3.x;
        a1.y += w2 * v2.y + w3 * v3.y;
    }
    for (; j < e; ++j) {
        int2 m0 = meta[j];
        float2 v0 = h2[m0.x * 64 + lane];
        float w0 = __int_as_float(m0.y);
        a0.x += w0 * v0.x;
        a0.y += w0 * v0.y;
    }
    ((float2*)out)[node * 64 + lane] = make_float2(a0.x + a1.x, a0.y + a1.y);
}

// ------------- fused matmul: out[80 x 64 tile] = sum_{hop} h_hop(80x128) @ W[hop] -------
// W layout [4][128][WSTRIDE]; this block handles cols cb*64..+63.
// EPI: 1 = +bias,relu   2 = +bias,log_softmax (WSTRIDE==64 only)
// 256 threads: tx = tid&15 (float4 col), ty = tid>>4 (5-row group). grid (625, WSTRIDE/64).
template <int WSTRIDE, int EPI>
__global__ __launch_bounds__(256) void mm_fused(const float* __restrict__ h0,
                                                const float* __restrict__ h1,
                                                const float* __restrict__ h2,
                                                const float* __restrict__ h3,
                                                const float* __restrict__ W,
                                                const float* __restrict__ bias,
                                                float* __restrict__ out) {
    __shared__ float hs[80 * 132];   // padded stride -> conflict-free b128 reads
    __shared__ float wsh[128 * 64];
    const int tid = threadIdx.x;
    const int tx = tid & 15;
    const int ty = tid >> 4;
    const int row0 = blockIdx.x * 80;
    const int cb = blockIdx.y;

    float acc[5][4];
#pragma unroll
    for (int r = 0; r < 5; ++r)
#pragma unroll
        for (int j = 0; j < 4; ++j) acc[r][j] = 0.f;

    const int rbase = ty * 5;

#pragma unroll
    for (int hop = 0; hop < 4; ++hop) {
        const float* hp = (hop == 0) ? h0 : (hop == 1) ? h1 : (hop == 2) ? h2 : h3;
        // stage h tile (2560 float4, coalesced)
        const float4* srcv = (const float4*)(hp + (size_t)row0 * 128);
        for (int i = tid; i < 2560; i += 256) {
            int r = i >> 5, c = i & 31;
            *(float4*)&hs[r * 132 + c * 4] = srcv[i];
        }
        // stage W panel: rows 0..127, cols cb*64..+63 of W[hop]
        const float* wp = W + (size_t)hop * 128 * WSTRIDE + cb * 64;
        for (int i = tid; i < 2048; i += 256) {
            int k = i >> 4, c = i & 15;
            *(float4*)&wsh[k * 64 + c * 4] = ((const float4*)(wp + (size_t)k * WSTRIDE))[c];
        }
        __syncthreads();

#pragma unroll 8
        for (int k4 = 0; k4 < 32; ++k4) {
            float4 wv0 = *(const float4*)&wsh[(k4 * 4 + 0) * 64 + tx * 4];
            float4 wv1 = *(const float4*)&wsh[(k4 * 4 + 1) * 64 + tx * 4];
            float4 wv2 = *(const float4*)&wsh[(k4 * 4 + 2) * 64 + tx * 4];
            float4 wv3 = *(const float4*)&wsh[(k4 * 4 + 3) * 64 + tx * 4];
#pragma unroll
            for (int r = 0; r < 5; ++r) {
                float4 hv = *(const float4*)&hs[(rbase + r) * 132 + k4 * 4];
                acc[r][0] += hv.x * wv0.x + hv.y * wv1.x + hv.z * wv2.x + hv.w * wv3.x;
                acc[r][1] += hv.x * wv0.y + hv.y * wv1.y + hv.z * wv2.y + hv.w * wv3.y;
                acc[r][2] += hv.x * wv0.z + hv.y * wv1.z + hv.z * wv2.z + hv.w * wv3.z;
                acc[r][3] += hv.x * wv0.w + hv.y * wv1.w + hv.z * wv2.w + hv.w * wv3.w;
            }
        }
        __syncthreads();   // protect LDS before next hop's restage
    }

    const int colg = cb * 64 + tx * 4;
    float4 bv = *(const float4*)&bias[colg];

#pragma unroll
    for (int r = 0; r < 5; ++r) {
        int rowg = row0 + rbase + r;
        float* op = out + (size_t)rowg * WSTRIDE + colg;
        float4 v = make_float4(acc[r][0] + bv.x, acc[r][1] + bv.y,
                               acc[r][2] + bv.z, acc[r][3] + bv.w);
        if (EPI == 1) {
            v.x = fmaxf(v.x, 0.f);
            v.y = fmaxf(v.y, 0.f);
            v.z = fmaxf(v.z, 0.f);
            v.w = fmaxf(v.w, 0.f);
            *(float4*)op = v;
        } else {  // EPI == 2: log_softmax over 64 cols (16 lanes x 4 each)
            float m = fmaxf(fmaxf(v.x, v.y), fmaxf(v.z, v.w));
            m = fmaxf(m, __shfl_xor(m, 1));
            m = fmaxf(m, __shfl_xor(m, 2));
            m = fmaxf(m, __shfl_xor(m, 4));
            m = fmaxf(m, __shfl_xor(m, 8));
            float su = expf(v.x - m) + expf(v.y - m) + expf(v.z - m) + expf(v.w - m);
            su += __shfl_xor(su, 1);
            su += __shfl_xor(su, 2);
            su += __shfl_xor(su, 4);
            su += __shfl_xor(su, 8);
            float l = m + logf(su);
            v.x -= l; v.y -= l; v.z -= l; v.w -= l;
            *(float4*)op = v;
        }
    }
}

// ---------------- launch ----------------

extern "C" void kernel_launch(void* const* d_in, const int* in_sizes, int n_in,
                              void* d_out, int out_size, void* d_ws, size_t ws_size,
                              hipStream_t stream) {
    const float* x  = (const float*)d_in[0];
    const int*   ei = (const int*)d_in[1];
    const float* W1 = (const float*)d_in[2];
    const float* b1 = (const float*)d_in[3];
    const float* W2 = (const float*)d_in[4];
    const float* b2 = (const float*)d_in[5];
    float* out = (float*)d_out;

    const int* row = ei;             // edge_index[0]
    const int* col = ei + N_EDGES;   // edge_index[1]

    char* ws_base = (char*)d_ws;
    size_t o = 0;
    auto carve = [&](size_t bytes) {
        void* p = ws_base + o;
        o = (o + bytes + 511) & ~(size_t)511;
        return p;
    };
    int*   deg    = (int*)carve(N_NODES * 4);
    float* dinv   = (float*)carve(N_NODES * 4);
    int*   off    = (int*)carve((N_NODES + 1) * 4);
    int*   cursor = (int*)carve(N_NODES * 4);
    int*   bsum   = (int*)carve(NB_SCAN * 4);
    int2*  meta   = (int2*)carve((size_t)N_EDGES * 8);
    float* A      = (float*)carve((size_t)N_NODES * FEAT * 4);
    float* B      = (float*)carve((size_t)N_NODES * FEAT * 4);
    float* C      = (float*)carve((size_t)N_NODES * FEAT * 4);
    float* hid    = (float*)carve((size_t)N_NODES * FEAT * 4);

    const int nb_e = (N_EDGES + 255) / 256;   // 3125
    const int nb_prop = N_NODES / 4;          // 12500

    // graph preprocessing
    hipMemsetAsync(deg, 0, N_NODES * 4, stream);
    count_deg_kernel<<<nb_e, 256, 0, stream>>>(col, deg, N_EDGES);
    scan1_kernel<<<NB_SCAN, 256, 0, stream>>>(deg, bsum, dinv);
    scan2_kernel<<<1, 256, 0, stream>>>(bsum);
    scan3_kernel<<<NB_SCAN, 256, 0, stream>>>(deg, bsum, off, cursor);
    scatter_csr_kernel<<<nb_e, 256, 0, stream>>>(row, col, dinv, cursor, meta, N_EDGES);

    // ----- layer 1: hid = relu(x@W1[0] + (Ax)@W1[1] + (A2x)@W1[2] + (A3x)@W1[3] + b1)
    prop_kernel<<<nb_prop, 256, 0, stream>>>(x, off, meta, A);
    prop_kernel<<<nb_prop, 256, 0, stream>>>(A, off, meta, B);
    prop_kernel<<<nb_prop, 256, 0, stream>>>(B, off, meta, C);
    mm_fused<128, 1><<<dim3(625, 2), 256, 0, stream>>>(x, A, B, C, W1, b1, hid);

    // ----- layer 2: out = log_softmax(hid@W2[0] + ... + (A3 hid)@W2[3] + b2)
    prop_kernel<<<nb_prop, 256, 0, stream>>>(hid, off, meta, A);
    prop_kernel<<<nb_prop, 256, 0, stream>>>(A, off, meta, B);
    prop_kernel<<<nb_prop, 256, 0, stream>>>(B, off, meta, C);
    mm_fused<64, 2><<<dim3(625, 1), 256, 0, stream>>>(hid, A, B, C, W2, b2, out);
}

// Round 4
// 602.237 us; speedup vs baseline: 1.7722x; 1.1874x over previous
//
#include <hip/hip_runtime.h>
#include <math.h>

// TAGConv 2-layer GNN on MI355X.
// R4: Horner restructure: out = y0 + A(y1 + A(y2 + A y3)), y_k = h @ W[k].
// - mm_y: single staged input tile (42KB LDS -> 3 blocks/CU), W from global (L2).
// - props carry the +y_k accumulate and the bias/relu/log_softmax epilogues.
// - layer-2 props act on 64-wide arrays (half the gather bytes), 2 nodes/wave.

#define N_NODES 50000
#define N_EDGES 800000
#define NB_SCAN 196          // ceil(50000/256)

// ---------------- graph preprocessing ----------------

__global__ void count_deg_kernel(const int* __restrict__ col, int* __restrict__ deg, int e) {
    int i = blockIdx.x * 256 + threadIdx.x;
    if (i < e) atomicAdd(&deg[col[i]], 1);
}

__global__ void scan1_kernel(const int* __restrict__ deg, int* __restrict__ bsum,
                             float* __restrict__ dinv) {
    __shared__ int sd[256];
    int tid = threadIdx.x;
    int i = blockIdx.x * 256 + tid;
    int v = (i < N_NODES) ? deg[i] : 0;
    if (i < N_NODES) dinv[i] = (v > 0) ? (1.0f / sqrtf((float)v)) : 0.f;
    sd[tid] = v;
    __syncthreads();
    for (int o = 128; o > 0; o >>= 1) {
        if (tid < o) sd[tid] += sd[tid + o];
        __syncthreads();
    }
    if (tid == 0) bsum[blockIdx.x] = sd[0];
}

__global__ void scan2_kernel(int* __restrict__ bsum) {
    __shared__ int sd[256];
    int tid = threadIdx.x;
    int v = (tid < NB_SCAN) ? bsum[tid] : 0;
    sd[tid] = v;
    __syncthreads();
    for (int o = 1; o < 256; o <<= 1) {
        int t = (tid >= o) ? sd[tid - o] : 0;
        __syncthreads();
        sd[tid] += t;
        __syncthreads();
    }
    if (tid < NB_SCAN) bsum[tid] = sd[tid] - v;   // exclusive
}

__global__ void scan3_kernel(const int* __restrict__ deg, const int* __restrict__ bsum,
                             int* __restrict__ off, int* __restrict__ cursor) {
    __shared__ int sd[256];
    int tid = threadIdx.x;
    int i = blockIdx.x * 256 + tid;
    int v = (i < N_NODES) ? deg[i] : 0;
    sd[tid] = v;
    __syncthreads();
    for (int o = 1; o < 256; o <<= 1) {
        int t = (tid >= o) ? sd[tid - o] : 0;
        __syncthreads();
        sd[tid] += t;
        __syncthreads();
    }
    if (i < N_NODES) {
        int val = bsum[blockIdx.x] + sd[tid] - v;
        off[i] = val;
        cursor[i] = val;
    }
    if (i == N_NODES - 1) off[N_NODES] = N_EDGES;
}

__global__ void scatter_csr_kernel(const int* __restrict__ row, const int* __restrict__ col,
                                   const float* __restrict__ dinv, int* __restrict__ cursor,
                                   int2* __restrict__ meta, int e) {
    int i = blockIdx.x * 256 + threadIdx.x;
    if (i < e) {
        int r = row[i], c = col[i];
        int p = atomicAdd(&cursor[c], 1);
        float w = dinv[r] * dinv[c];
        meta[p] = make_int2(r, __float_as_int(w));
    }
}

// ---------------- mm_y: y[hop] = h @ W[hop], hop = blockIdx&3 ----------------
// 80-row tile staged in LDS (42KB -> 3 blocks/CU); W read from global (L2-resident).
// 256 threads = 16 tx (col quads) x 16 ty (5-row groups).
// WOUT=128: thread covers col quads {tx*4, 64+tx*4}; WOUT=64: {tx*4}.
template <int WOUT>
__global__ __launch_bounds__(256) void mm_y(const float* __restrict__ h,
                                            const float* __restrict__ W,   // [4][128][WOUT]
                                            float* __restrict__ y) {       // [4][N][WOUT]
    constexpr int NQ = WOUT / 64;   // quads per thread
    __shared__ float hs[80 * 132];
    const int tid = threadIdx.x;
    const int tx = tid & 15;
    const int ty = tid >> 4;
    const int tile = blockIdx.x >> 2;
    const int hop = blockIdx.x & 3;
    const int row0 = tile * 80;

    // stage h tile (2560 float4, coalesced)
    const float4* srcv = (const float4*)(h + (size_t)row0 * 128);
    for (int i = tid; i < 2560; i += 256) {
        int r = i >> 5, c = i & 31;
        *(float4*)&hs[r * 132 + c * 4] = srcv[i];
    }
    __syncthreads();

    const float4* Wv = (const float4*)(W + (size_t)hop * 128 * WOUT);

    float4 acc[5][NQ];
#pragma unroll
    for (int r = 0; r < 5; ++r)
#pragma unroll
        for (int q = 0; q < NQ; ++q) acc[r][q] = make_float4(0.f, 0.f, 0.f, 0.f);

    const int rbase = ty * 5;
#pragma unroll 2
    for (int k4 = 0; k4 < 32; ++k4) {
        float4 wv[4][NQ];
#pragma unroll
        for (int kk = 0; kk < 4; ++kk)
#pragma unroll
            for (int q = 0; q < NQ; ++q)
                wv[kk][q] = Wv[(size_t)(k4 * 4 + kk) * (WOUT / 4) + q * 16 + tx];
#pragma unroll
        for (int r = 0; r < 5; ++r) {
            float4 hv = *(const float4*)&hs[(rbase + r) * 132 + k4 * 4];
#pragma unroll
            for (int q = 0; q < NQ; ++q) {
                acc[r][q].x += hv.x * wv[0][q].x + hv.y * wv[1][q].x + hv.z * wv[2][q].x + hv.w * wv[3][q].x;
                acc[r][q].y += hv.x * wv[0][q].y + hv.y * wv[1][q].y + hv.z * wv[2][q].y + hv.w * wv[3][q].y;
                acc[r][q].z += hv.x * wv[0][q].z + hv.y * wv[1][q].z + hv.z * wv[2][q].z + hv.w * wv[3][q].z;
                acc[r][q].w += hv.x * wv[0][q].w + hv.y * wv[1][q].w + hv.z * wv[2][q].w + hv.w * wv[3][q].w;
            }
        }
    }

    float* yp = y + (size_t)hop * N_NODES * WOUT;
#pragma unroll
    for (int r = 0; r < 5; ++r) {
        float* op = yp + (size_t)(row0 + rbase + r) * WOUT;
#pragma unroll
        for (int q = 0; q < NQ; ++q)
            *(float4*)&op[q * 64 + tx * 4] = acc[r][q];
    }
}

// -------- prop128: out = A*h + yadd (+relu+bias). 1 node / 64-lane wave (float2/lane).
template <int EPI>   // 0 = plain accumulate, 1 = +bias, relu
__global__ void prop128(const float* __restrict__ h, const int* __restrict__ off,
                        const int2* __restrict__ meta, const float* __restrict__ yadd,
                        const float* __restrict__ bias, float* __restrict__ out) {
    int node = blockIdx.x * 4 + (threadIdx.x >> 6);
    int lane = threadIdx.x & 63;
    int s = off[node], e = off[node + 1];
    const float2* h2 = (const float2*)h;
    float2 a0 = make_float2(0.f, 0.f), a1 = make_float2(0.f, 0.f);
    int j = s;
    for (; j + 3 < e; j += 4) {
        int2 m0 = meta[j], m1 = meta[j + 1], m2 = meta[j + 2], m3 = meta[j + 3];
        float2 v0 = h2[m0.x * 64 + lane];
        float2 v1 = h2[m1.x * 64 + lane];
        float2 v2 = h2[m2.x * 64 + lane];
        float2 v3 = h2[m3.x * 64 + lane];
        float w0 = __int_as_float(m0.y), w1 = __int_as_float(m1.y);
        float w2 = __int_as_float(m2.y), w3 = __int_as_float(m3.y);
        a0.x += w0 * v0.x + w1 * v1.x;
        a0.y += w0 * v0.y + w1 * v1.y;
        a1.x += w2 * v2.x + w3 * v3.x;
        a1.y += w2 * v2.y + w3 * v3.y;
    }
    for (; j < e; ++j) {
        int2 m0 = meta[j];
        float2 v0 = h2[m0.x * 64 + lane];
        float w0 = __int_as_float(m0.y);
        a0.x += w0 * v0.x;
        a0.y += w0 * v0.y;
    }
    float2 yv = ((const float2*)yadd)[node * 64 + lane];
    float2 r = make_float2(a0.x + a1.x + yv.x, a0.y + a1.y + yv.y);
    if (EPI == 1) {
        float2 bv = ((const float2*)bias)[lane];
        r.x = fmaxf(r.x + bv.x, 0.f);
        r.y = fmaxf(r.y + bv.y, 0.f);
    }
    ((float2*)out)[node * 64 + lane] = r;
}

// -------- prop64: 64-wide arrays, 2 nodes / wave (32 lanes x float2 each).
template <int EPI>   // 0 = plain accumulate, 2 = +bias, log_softmax
__global__ void prop64(const float* __restrict__ h, const int* __restrict__ off,
                       const int2* __restrict__ meta, const float* __restrict__ yadd,
                       const float* __restrict__ bias, float* __restrict__ out) {
    int tid = threadIdx.x;
    int node = blockIdx.x * 8 + (tid >> 5);
    int l32 = tid & 31;
    int s = off[node], e = off[node + 1];
    const float2* h2 = (const float2*)h;   // 32 float2 per 64-wide row
    float2 a0 = make_float2(0.f, 0.f), a1 = make_float2(0.f, 0.f);
    int j = s;
    for (; j + 3 < e; j += 4) {
        int2 m0 = meta[j], m1 = meta[j + 1], m2 = meta[j + 2], m3 = meta[j + 3];
        float2 v0 = h2[m0.x * 32 + l32];
        float2 v1 = h2[m1.x * 32 + l32];
        float2 v2 = h2[m2.x * 32 + l32];
        float2 v3 = h2[m3.x * 32 + l32];
        float w0 = __int_as_float(m0.y), w1 = __int_as_float(m1.y);
        float w2 = __int_as_float(m2.y), w3 = __int_as_float(m3.y);
        a0.x += w0 * v0.x + w1 * v1.x;
        a0.y += w0 * v0.y + w1 * v1.y;
        a1.x += w2 * v2.x + w3 * v3.x;
        a1.y += w2 * v2.y + w3 * v3.y;
    }
    for (; j < e; ++j) {
        int2 m0 = meta[j];
        float2 v0 = h2[m0.x * 32 + l32];
        float w0 = __int_as_float(m0.y);
        a0.x += w0 * v0.x;
        a0.y += w0 * v0.y;
    }
    float2 yv = ((const float2*)yadd)[node * 32 + l32];
    float2 v = make_float2(a0.x + a1.x + yv.x, a0.y + a1.y + yv.y);
    if (EPI == 2) {
        float2 bv = ((const float2*)bias)[l32];
        v.x += bv.x; v.y += bv.y;
        float m = fmaxf(v.x, v.y);
        for (int d = 1; d < 32; d <<= 1) m = fmaxf(m, __shfl_xor(m, d));
        float su = expf(v.x - m) + expf(v.y - m);
        for (int d = 1; d < 32; d <<= 1) su += __shfl_xor(su, d);
        float l = m + logf(su);
        v.x -= l; v.y -= l;
    }
    ((float2*)out)[node * 32 + l32] = v;
}

// ---------------- launch ----------------

extern "C" void kernel_launch(void* const* d_in, const int* in_sizes, int n_in,
                              void* d_out, int out_size, void* d_ws, size_t ws_size,
                              hipStream_t stream) {
    const float* x  = (const float*)d_in[0];
    const int*   ei = (const int*)d_in[1];
    const float* W1 = (const float*)d_in[2];
    const float* b1 = (const float*)d_in[3];
    const float* W2 = (const float*)d_in[4];
    const float* b2 = (const float*)d_in[5];
    float* out = (float*)d_out;

    const int* row = ei;             // edge_index[0]
    const int* col = ei + N_EDGES;   // edge_index[1]

    char* ws_base = (char*)d_ws;
    size_t o = 0;
    auto carve = [&](size_t bytes) {
        void* p = ws_base + o;
        o = (o + bytes + 511) & ~(size_t)511;
        return p;
    };
    int*   deg    = (int*)carve(N_NODES * 4);
    float* dinv   = (float*)carve(N_NODES * 4);
    int*   off    = (int*)carve((N_NODES + 1) * 4);
    int*   cursor = (int*)carve(N_NODES * 4);
    int*   bsum   = (int*)carve(NB_SCAN * 4);
    int2*  meta   = (int2*)carve((size_t)N_EDGES * 8);
    float* y1     = (float*)carve((size_t)4 * N_NODES * 128 * 4);   // [4][N][128]
    float* T      = (float*)carve((size_t)N_NODES * 128 * 4);

    // layer-1 slot aliases
    float* y1_0 = y1;
    float* y1_1 = y1 + (size_t)1 * N_NODES * 128;
    float* y1_2 = y1 + (size_t)2 * N_NODES * 128;
    float* y1_3 = y1 + (size_t)3 * N_NODES * 128;
    float* S    = y1_3;     // reused after y1_3 consumed
    float* HID  = T;        // reused after T consumed
    // layer-2 aliases (y1 region is free once layer 1 is done)
    float* y2   = y1;                                  // [4][N][64]
    float* y2_0 = y2;
    float* y2_1 = y2 + (size_t)1 * N_NODES * 64;
    float* y2_2 = y2 + (size_t)2 * N_NODES * 64;
    float* y2_3 = y2 + (size_t)3 * N_NODES * 64;
    float* T2   = y2 + (size_t)4 * N_NODES * 64;
    float* S2   = y2_3;

    const int nb_e = (N_EDGES + 255) / 256;   // 3125

    // graph preprocessing
    hipMemsetAsync(deg, 0, N_NODES * 4, stream);
    count_deg_kernel<<<nb_e, 256, 0, stream>>>(col, deg, N_EDGES);
    scan1_kernel<<<NB_SCAN, 256, 0, stream>>>(deg, bsum, dinv);
    scan2_kernel<<<1, 256, 0, stream>>>(bsum);
    scan3_kernel<<<NB_SCAN, 256, 0, stream>>>(deg, bsum, off, cursor);
    scatter_csr_kernel<<<nb_e, 256, 0, stream>>>(row, col, dinv, cursor, meta, N_EDGES);

    // ----- layer 1 (Horner): hid = relu(y0 + A(y1 + A(y2 + A y3)) + b1)
    mm_y<128><<<2500, 256, 0, stream>>>(x, W1, y1);
    prop128<0><<<12500, 256, 0, stream>>>(y1_3, off, meta, y1_2, nullptr, T);
    prop128<0><<<12500, 256, 0, stream>>>(T,    off, meta, y1_1, nullptr, S);
    prop128<1><<<12500, 256, 0, stream>>>(S,    off, meta, y1_0, b1,      HID);

    // ----- layer 2 (Horner): out = log_softmax(z0 + A(z1 + A(z2 + A z3)) + b2)
    mm_y<64><<<2500, 256, 0, stream>>>(HID, W2, y2);
    prop64<0><<<6250, 256, 0, stream>>>(y2_3, off, meta, y2_2, nullptr, T2);
    prop64<0><<<6250, 256, 0, stream>>>(T2,   off, meta, y2_1, nullptr, S2);
    prop64<2><<<6250, 256, 0, stream>>>(S2,   off, meta, y2_0, b2,      out);
}